// Round 2
// baseline (334.049 us; speedup 1.0000x reference)
//
#include <hip/hip_runtime.h>

#define B   64
#define K   512
#define C   4
#define NL  5
#define NCH 64          // j-chunks for the transposed matvec partials (8 j's each)
#define BK  (B*K)

typedef _Float16 half_t;
typedef _Float16 half8 __attribute__((ext_vector_type(8)));

// ---------------------------------------------------------------------------
// Precompute: Habs2 = h_re^2 + h_im^2 as fp16 (33.5 MB, L3-resident).
// Pure streaming: 8 elements/thread, 2x float4 loads per input, 1x half8 store.
// ---------------------------------------------------------------------------
__global__ __launch_bounds__(256) void k_pre(const float* __restrict__ hre,
                                             const float* __restrict__ him,
                                             half_t* __restrict__ habs) {
    size_t t    = (size_t)blockIdx.x * blockDim.x + threadIdx.x;
    size_t base = t * 8;
    const float4* r4 = (const float4*)(hre + base);
    const float4* i4 = (const float4*)(him + base);
    float4 r0 = r4[0], r1 = r4[1];
    float4 i0 = i4[0], i1 = i4[1];
    half8 h;
    h[0] = (_Float16)(r0.x * r0.x + i0.x * i0.x);
    h[1] = (_Float16)(r0.y * r0.y + i0.y * i0.y);
    h[2] = (_Float16)(r0.z * r0.z + i0.z * i0.z);
    h[3] = (_Float16)(r0.w * r0.w + i0.w * i0.w);
    h[4] = (_Float16)(r1.x * r1.x + i1.x * i1.x);
    h[5] = (_Float16)(r1.y * r1.y + i1.y * i1.y);
    h[6] = (_Float16)(r1.z * r1.z + i1.z * i1.z);
    h[7] = (_Float16)(r1.w * r1.w + i1.w * i1.w);
    *(half8*)(habs + base) = h;
}

// ---------------------------------------------------------------------------
// Init: v state, xsq = |v|^2, and dabs2 = |H_diag|^2 (strided diagonal reads,
// tiny: 32768 threads x 8 B).
// ---------------------------------------------------------------------------
__global__ __launch_bounds__(256) void k_init(const float* __restrict__ vre,
                                              const float* __restrict__ vim,
                                              const float* __restrict__ hre,
                                              const float* __restrict__ him,
                                              float2* __restrict__ vstate,
                                              float* __restrict__ xsq,
                                              float* __restrict__ dabs2) {
    int t = blockIdx.x * blockDim.x + threadIdx.x;
    float a = vre[t], b = vim[t];
    vstate[t] = make_float2(a, b);
    xsq[t]    = a * a + b * b;
    int bb = t >> 9, k = t & (K - 1);
    size_t d = (size_t)bb * K * K + (size_t)k * K + k;
    float dr = hre[d], di = him[d];
    dabs2[t] = dr * dr + di * di;
}

// ---------------------------------------------------------------------------
// K1: cov[b,j] = Habs2[b,j,:] . xsq[b,:] + noise, then the fused real-algebra
// u/w step:  A = |d|^2*xsq_j ; w = cov/(cov-A) (real) ; vtilde = (|d|^2 w/cov) v
//            ulvec = A*w/cov^2
// One wave per 8 rows, lane covers 8 consecutive fp16 columns; all 8 row
// loads issued before the reduce chains.
// ---------------------------------------------------------------------------
__global__ __launch_bounds__(256) void k_cov(const half_t* __restrict__ habs,
                                             const float* __restrict__ xsq,
                                             const float* __restrict__ noise,
                                             const float* __restrict__ dabs2,
                                             const float2* __restrict__ vstate,
                                             float* __restrict__ ulvec,
                                             float2* __restrict__ vtilde) {
    int lane = threadIdx.x & 63;
    int wv   = threadIdx.x >> 6;
    int b    = blockIdx.x >> 4;       // 16 row-blocks per batch
    int rblk = blockIdx.x & 15;
    int j0   = rblk * 32 + wv * 8;

    const float4* x4 = (const float4*)(xsq + b * K);
    float4 xa = x4[lane * 2];
    float4 xb = x4[lane * 2 + 1];

    half8 h[8];
    const half8* rp = (const half8*)(habs + ((size_t)b * K + j0) * K);
#pragma unroll
    for (int r = 0; r < 8; ++r) h[r] = rp[r * (K / 8) + lane];

#pragma unroll
    for (int r = 0; r < 8; ++r) {
        float acc = (float)h[r][0] * xa.x + (float)h[r][1] * xa.y +
                    (float)h[r][2] * xa.z + (float)h[r][3] * xa.w +
                    (float)h[r][4] * xb.x + (float)h[r][5] * xb.y +
                    (float)h[r][6] * xb.z + (float)h[r][7] * xb.w;
#pragma unroll
        for (int off = 32; off; off >>= 1) acc += __shfl_xor(acc, off, 64);
        if (lane == 0) {
            int bj    = b * K + j0 + r;
            float cov = acc + noise[bj];
            float A   = dabs2[bj] * xsq[bj];
            float w   = cov / (cov - A);
            float s   = dabs2[bj] * w / cov;
            float2 vv = vstate[bj];
            vtilde[bj] = make_float2(s * vv.x, s * vv.y);
            ulvec[bj]  = A * w / (cov * cov);
        }
    }
}

// ---------------------------------------------------------------------------
// K2: transposed matvec partials: ulpart[jc][b][k] = sum_{j in 8-chunk jc}
//     Habs2[b,j,k] * ulvec[b,j].  One wave per (b, jc); lane owns 8
//     consecutive columns (16 B loads, fully coalesced). Grid 1024 blocks
//     -> 4 waves/SIMD for latency hiding. No atomics.
// ---------------------------------------------------------------------------
__global__ __launch_bounds__(256) void k_tmv(const half_t* __restrict__ habs,
                                             const float* __restrict__ ulvec,
                                             float* __restrict__ ulpart) {
    int lane = threadIdx.x & 63;
    int wv   = threadIdx.x >> 6;
    int task = blockIdx.x * 4 + wv;   // B*NCH tasks
    int b    = task >> 6;             // / NCH
    int jc   = task & (NCH - 1);

    float acc[8] = {0.f, 0.f, 0.f, 0.f, 0.f, 0.f, 0.f, 0.f};
    const half8* base = (const half8*)(habs + ((size_t)b * K + jc * 8) * K);
    const float* ulv  = ulvec + b * K + jc * 8;
#pragma unroll
    for (int jj = 0; jj < 8; ++jj) {
        half8 h  = base[jj * (K / 8) + lane];
        float ul = ulv[jj];                    // wave-uniform
#pragma unroll
        for (int q = 0; q < 8; ++q) acc[q] += (float)h[q] * ul;
    }
    float* outp = ulpart + ((size_t)jc * B + b) * K + lane * 8;
    ((float4*)outp)[0] = make_float4(acc[0], acc[1], acc[2], acc[3]);
    ((float4*)outp)[1] = make_float4(acc[4], acc[5], acc[6], acc[7]);
}

// ---------------------------------------------------------------------------
// K3: finish — sum partials, mu/ula, ar/dl mix, CReLU, rc recombine, power
// correction; write new v state, xsq, and this layer's output slice.
// ---------------------------------------------------------------------------
__global__ __launch_bounds__(256) void k_fin(const float* __restrict__ ulpart,
                                             const float2* __restrict__ vtilde,
                                             const float* __restrict__ maxpow,
                                             const float* __restrict__ ar_re,
                                             const float* __restrict__ ar_im,
                                             const float* __restrict__ dl_re,
                                             const float* __restrict__ dl_im,
                                             const float* __restrict__ rc_re,
                                             const float* __restrict__ rc_im,
                                             float2* __restrict__ vstate,
                                             float* __restrict__ xsq,
                                             float* __restrict__ out) {
    int t = blockIdx.x * blockDim.x + threadIdx.x;
    float ul = 0.f;
#pragma unroll
    for (int jc = 0; jc < NCH; ++jc) ul += ulpart[jc * BK + t];

    float2 vt = vtilde[t];
    float  p  = maxpow[t];
    float avt = sqrtf(vt.x * vt.x + vt.y * vt.y);
    float mu  = fmaxf(avt / sqrtf(p) - ul, 0.f);
    float ula = ul + mu;
    float inv = 1.f / ula;

    float ax = 0.f, ay = 0.f;
#pragma unroll
    for (int c = 0; c < C; ++c) {
        float gre = ar_re[c] * inv + dl_re[c];
        float gim = ar_im[c] * inv + dl_im[c];
        float zre = vt.x * gre - vt.y * gim;   // vt * g
        float zim = vt.x * gim + vt.y * gre;
        zre = fmaxf(zre, 0.f);                 // CReLU
        zim = fmaxf(zim, 0.f);
        ax += zre * rc_re[c] - zim * rc_im[c]; // += z * rc
        ay += zre * rc_im[c] + zim * rc_re[c];
    }
    float n2   = ax * ax + ay * ay;
    float cur  = fmaxf(p, n2);
    float corr = fminf(sqrtf(p / cur), 1.f);
    ax *= corr;
    ay *= corr;
    vstate[t] = make_float2(ax, ay);
    xsq[t]    = ax * ax + ay * ay;
    out[2 * t]     = ax;
    out[2 * t + 1] = ay;
}

// ---------------------------------------------------------------------------
extern "C" void kernel_launch(void* const* d_in, const int* in_sizes, int n_in,
                              void* d_out, int out_size, void* d_ws, size_t ws_size,
                              hipStream_t stream) {
    const float* hre   = (const float*)d_in[0];
    const float* him   = (const float*)d_in[1];
    const float* noise = (const float*)d_in[2];
    const float* mp    = (const float*)d_in[3];
    const float* vre   = (const float*)d_in[4];
    const float* vim   = (const float*)d_in[5];
    const float* ar_re = (const float*)d_in[6];
    const float* ar_im = (const float*)d_in[7];
    const float* dl_re = (const float*)d_in[8];
    const float* dl_im = (const float*)d_in[9];
    const float* rc_re = (const float*)d_in[10];
    const float* rc_im = (const float*)d_in[11];
    float* out = (float*)d_out;

    char*   ws     = (char*)d_ws;
    size_t  off    = 0;
    half_t* habs   = (half_t*)(ws + off); off += (size_t)BK * K * 2;  // 33.5 MB
    float*  dabs2  = (float*) (ws + off); off += (size_t)BK * 4;
    float2* vstate = (float2*)(ws + off); off += (size_t)BK * 8;
    float*  xsq    = (float*) (ws + off); off += (size_t)BK * 4;
    float*  ulvec  = (float*) (ws + off); off += (size_t)BK * 4;
    float2* vtilde = (float2*)(ws + off); off += (size_t)BK * 8;
    float*  ulpart = (float*) (ws + off); off += (size_t)NCH * BK * 4; // 8.4 MB

    k_pre <<<(size_t)BK * K / 8 / 256, 256, 0, stream>>>(hre, him, habs);
    k_init<<<BK / 256, 256, 0, stream>>>(vre, vim, hre, him, vstate, xsq, dabs2);

    for (int l = 0; l < NL; ++l) {
        k_cov<<<B * 16, 256, 0, stream>>>(habs, xsq, noise, dabs2, vstate,
                                          ulvec, vtilde);
        k_tmv<<<B * NCH / 4, 256, 0, stream>>>(habs, ulvec, ulpart);
        k_fin<<<BK / 256, 256, 0, stream>>>(ulpart, vtilde, mp,
                                            ar_re, ar_im, dl_re, dl_im,
                                            rc_re, rc_im,
                                            vstate, xsq,
                                            out + (size_t)l * BK * 2);
    }
}

// Round 4
// 222.050 us; speedup vs baseline: 1.5044x; 1.5044x over previous
//
#include <hip/hip_runtime.h>

#define B   64
#define K   512
#define C   4
#define NL  5
#define NCH 32          // 32 chunks x 16 rows = 512
#define BK  (B*K)

typedef _Float16 half_t;
typedef _Float16 half8 __attribute__((ext_vector_type(8)));
typedef float    f4    __attribute__((ext_vector_type(4)));

// ---------------------------------------------------------------------------
// Precompute: Habs2 = h_re^2 + h_im^2 as fp16 (33.5 MB, L3-resident) + the
// diagonal |H_bkk|^2. Nontemporal loads: h_re/h_im are read once; keep L3
// space for habs which is re-read 5x.
// ---------------------------------------------------------------------------
__global__ __launch_bounds__(256) void k_pre(const float* __restrict__ hre,
                                             const float* __restrict__ him,
                                             half_t* __restrict__ habs,
                                             float* __restrict__ dabs2) {
    size_t t    = (size_t)blockIdx.x * blockDim.x + threadIdx.x;
    size_t base = t * 8;
    const f4* r4 = (const f4*)(hre + base);
    const f4* i4 = (const f4*)(him + base);
    f4 r0 = __builtin_nontemporal_load(r4);
    f4 r1 = __builtin_nontemporal_load(r4 + 1);
    f4 i0 = __builtin_nontemporal_load(i4);
    f4 i1 = __builtin_nontemporal_load(i4 + 1);
    float s[8];
    s[0] = r0.x * r0.x + i0.x * i0.x;
    s[1] = r0.y * r0.y + i0.y * i0.y;
    s[2] = r0.z * r0.z + i0.z * i0.z;
    s[3] = r0.w * r0.w + i0.w * i0.w;
    s[4] = r1.x * r1.x + i1.x * i1.x;
    s[5] = r1.y * r1.y + i1.y * i1.y;
    s[6] = r1.z * r1.z + i1.z * i1.z;
    s[7] = r1.w * r1.w + i1.w * i1.w;
    half8 h;
#pragma unroll
    for (int q = 0; q < 8; ++q) h[q] = (_Float16)s[q];
    *(half8*)(habs + base) = h;

    // diagonal extraction: thread covers 8 consecutive elements of one row
    int col0 = (int)(base & (K - 1));
    int row  = (int)((base >> 9) & (K - 1));
    if (row >= col0 && row < col0 + 8) {
        size_t b = base >> 18;
        dabs2[b * K + row] = s[row - col0];
    }
}

// ---------------------------------------------------------------------------
// Init: v state (float2) and xsq = |v|^2
// ---------------------------------------------------------------------------
__global__ __launch_bounds__(256) void k_init(const float* __restrict__ vre,
                                              const float* __restrict__ vim,
                                              float2* __restrict__ vstate,
                                              float* __restrict__ xsq) {
    int t = blockIdx.x * blockDim.x + threadIdx.x;
    float a = vre[t], b = vim[t];
    vstate[t] = make_float2(a, b);
    xsq[t]    = a * a + b * b;
}

// ---------------------------------------------------------------------------
// Fused cov + transposed-matvec for one 16-row chunk of one batch.
// Block (b, jc): 4 waves, wave w owns rows j0=jc*16+w*4 .. +3.
// Phase 1: lane owns 8 consecutive cols (16 B fp16 load per row); row-sum via
//   butterfly shuffle; lanes 0-3 compute the per-row u/w algebra in parallel:
//     A = |d|^2 xsq ; w = cov/(cov-A) (real!) ; vtilde = (|d|^2 w/cov) v
//     ulvec = A w / cov^2   -> LDS only
// Phase 2: REUSE the phase-1 register fragments (same lane->column mapping!)
//   for the transposed matvec over this chunk; cross-wave sum via 8 KB LDS;
//   write ulpart[jc][b][:] coalesced.
// habs is read exactly ONCE per layer. Grid: B*NCH = 2048 blocks.
// ---------------------------------------------------------------------------
__global__ __launch_bounds__(256) void k_layer1(const half_t* __restrict__ habs,
                                                const float* __restrict__ xsq,
                                                const float* __restrict__ noise,
                                                const float* __restrict__ dabs2,
                                                const float2* __restrict__ vstate,
                                                float2* __restrict__ vtilde,
                                                float* __restrict__ ulpart) {
    int lane = threadIdx.x & 63;
    int wv   = threadIdx.x >> 6;
    int b    = blockIdx.x >> 5;
    int jc   = blockIdx.x & (NCH - 1);
    int j0   = jc * 16 + wv * 4;

    __shared__ float uls[16];
    __shared__ float part[4][K];

    const float4* x4 = (const float4*)(xsq + b * K);
    float4 xa = x4[lane * 2];
    float4 xb = x4[lane * 2 + 1];

    half8 h[4];
    const half8* rp = (const half8*)(habs + ((size_t)b * K + j0) * K);
#pragma unroll
    for (int r = 0; r < 4; ++r) h[r] = rp[r * (K / 8) + lane];

    float rs[4];
#pragma unroll
    for (int r = 0; r < 4; ++r) {
        float acc = (float)h[r][0] * xa.x + (float)h[r][1] * xa.y +
                    (float)h[r][2] * xa.z + (float)h[r][3] * xa.w +
                    (float)h[r][4] * xb.x + (float)h[r][5] * xb.y +
                    (float)h[r][6] * xb.z + (float)h[r][7] * xb.w;
#pragma unroll
        for (int off = 32; off; off >>= 1) acc += __shfl_xor(acc, off, 64);
        rs[r] = acc;   // all lanes hold the row sum
    }

    if (lane < 4) {
        float s  = (lane == 0) ? rs[0] : (lane == 1) ? rs[1]
                 : (lane == 2) ? rs[2] : rs[3];
        int bj   = b * K + j0 + lane;
        float cov = s + noise[bj];
        float A   = dabs2[bj] * xsq[bj];
        float w   = cov / (cov - A);
        float sc  = dabs2[bj] * w / cov;
        float2 vv = vstate[bj];
        vtilde[bj] = make_float2(sc * vv.x, sc * vv.y);
        uls[wv * 4 + lane] = A * w / (cov * cov);
    }
    __syncthreads();

    float u0 = uls[wv * 4 + 0];
    float u1 = uls[wv * 4 + 1];
    float u2 = uls[wv * 4 + 2];
    float u3 = uls[wv * 4 + 3];
    float* pw = &part[wv][lane * 8];
#pragma unroll
    for (int q = 0; q < 8; ++q) {
        pw[q] = (float)h[0][q] * u0 + (float)h[1][q] * u1 +
                (float)h[2][q] * u2 + (float)h[3][q] * u3;
    }
    __syncthreads();

    // 256 threads x 2 consecutive cols: sum 4 wave-partials, write coalesced
    int c = threadIdx.x * 2;
    float s0 = part[0][c]     + part[1][c]     + part[2][c]     + part[3][c];
    float s1 = part[0][c + 1] + part[1][c + 1] + part[2][c + 1] + part[3][c + 1];
    ((float2*)(ulpart + ((size_t)jc * B + b) * K))[threadIdx.x] = make_float2(s0, s1);
}

// ---------------------------------------------------------------------------
// K3: finish — sum 32 coalesced partial streams, mu/ula, ar/dl mix, CReLU,
// rc recombine, power correction; write new state + layer output.
// Grid: 256 blocks x 128 threads.
// ---------------------------------------------------------------------------
__global__ __launch_bounds__(128) void k_fin(const float* __restrict__ ulpart,
                                             const float2* __restrict__ vtilde,
                                             const float* __restrict__ maxpow,
                                             const float* __restrict__ ar_re,
                                             const float* __restrict__ ar_im,
                                             const float* __restrict__ dl_re,
                                             const float* __restrict__ dl_im,
                                             const float* __restrict__ rc_re,
                                             const float* __restrict__ rc_im,
                                             float2* __restrict__ vstate,
                                             float* __restrict__ xsq,
                                             float* __restrict__ out) {
    int t = blockIdx.x * blockDim.x + threadIdx.x;
    float ul = 0.f;
#pragma unroll
    for (int jc = 0; jc < NCH; ++jc) ul += ulpart[jc * BK + t];

    float2 vt = vtilde[t];
    float  p  = maxpow[t];
    float avt = sqrtf(vt.x * vt.x + vt.y * vt.y);
    float mu  = fmaxf(avt / sqrtf(p) - ul, 0.f);
    float ula = ul + mu;
    float inv = 1.f / ula;

    float ax = 0.f, ay = 0.f;
#pragma unroll
    for (int c = 0; c < C; ++c) {
        float gre = ar_re[c] * inv + dl_re[c];
        float gim = ar_im[c] * inv + dl_im[c];
        float zre = vt.x * gre - vt.y * gim;   // vt * g
        float zim = vt.x * gim + vt.y * gre;
        zre = fmaxf(zre, 0.f);                 // CReLU
        zim = fmaxf(zim, 0.f);
        ax += zre * rc_re[c] - zim * rc_im[c]; // += z * rc
        ay += zre * rc_im[c] + zim * rc_re[c];
    }
    float n2   = ax * ax + ay * ay;
    float cur  = fmaxf(p, n2);
    float corr = fminf(sqrtf(p / cur), 1.f);
    ax *= corr;
    ay *= corr;
    vstate[t] = make_float2(ax, ay);
    xsq[t]    = ax * ax + ay * ay;
    out[2 * t]     = ax;
    out[2 * t + 1] = ay;
}

// ---------------------------------------------------------------------------
extern "C" void kernel_launch(void* const* d_in, const int* in_sizes, int n_in,
                              void* d_out, int out_size, void* d_ws, size_t ws_size,
                              hipStream_t stream) {
    const float* hre   = (const float*)d_in[0];
    const float* him   = (const float*)d_in[1];
    const float* noise = (const float*)d_in[2];
    const float* mp    = (const float*)d_in[3];
    const float* vre   = (const float*)d_in[4];
    const float* vim   = (const float*)d_in[5];
    const float* ar_re = (const float*)d_in[6];
    const float* ar_im = (const float*)d_in[7];
    const float* dl_re = (const float*)d_in[8];
    const float* dl_im = (const float*)d_in[9];
    const float* rc_re = (const float*)d_in[10];
    const float* rc_im = (const float*)d_in[11];
    float* out = (float*)d_out;

    char*   ws     = (char*)d_ws;
    size_t  off    = 0;
    half_t* habs   = (half_t*)(ws + off); off += (size_t)BK * K * 2;  // 33.5 MB
    float*  dabs2  = (float*) (ws + off); off += (size_t)BK * 4;
    float2* vstate = (float2*)(ws + off); off += (size_t)BK * 8;
    float*  xsq    = (float*) (ws + off); off += (size_t)BK * 4;
    float2* vtilde = (float2*)(ws + off); off += (size_t)BK * 8;
    float*  ulpart = (float*) (ws + off); off += (size_t)NCH * BK * 4; // 4.2 MB

    k_pre <<<(size_t)BK * K / 8 / 256, 256, 0, stream>>>(hre, him, habs, dabs2);
    k_init<<<BK / 256, 256, 0, stream>>>(vre, vim, vstate, xsq);

    for (int l = 0; l < NL; ++l) {
        k_layer1<<<B * NCH, 256, 0, stream>>>(habs, xsq, noise, dabs2, vstate,
                                              vtilde, ulpart);
        k_fin<<<BK / 128, 128, 0, stream>>>(ulpart, vtilde, mp,
                                            ar_re, ar_im, dl_re, dl_im,
                                            rc_re, rc_im,
                                            vstate, xsq,
                                            out + (size_t)l * BK * 2);
    }
}